// Round 16
// baseline (399.852 us; speedup 1.0000x reference)
//
#include <hip/hip_runtime.h>

#define HID 128
#define MASKV -1000000000.0f
#define INV_TAU 2.0f
#define NB_SHIFT 9          // bucket = dst >> 9 (512 nodes/bucket)
#define NBMAX 256
#define ECHUNK 4096
#define BCAP 10240          // fixed per-bucket capacity (mean ~8163, >20 sigma headroom)
#define FP8_SCALE 16.0f
#define FP8_INV_SCALE 0.0625f

using short8 = __attribute__((ext_vector_type(8))) short;
using f32x4  = __attribute__((ext_vector_type(4))) float;
using f32x2  = __attribute__((ext_vector_type(2))) float;

// ---------- bf16 helpers ----------
__device__ inline ushort f2bf(float f) {
  unsigned u = __float_as_uint(f);
  return (ushort)((u + 0x7FFFu + ((u >> 16) & 1u)) >> 16);
}
__device__ inline float bflo(unsigned u) { return __uint_as_float(u << 16); }
__device__ inline float bfhi(unsigned u) { return __uint_as_float(u & 0xFFFF0000u); }

// ---------- fp8 e4m3 helpers (HW cvt) ----------
__device__ inline unsigned char f2fp8(float v) {
  int p = __builtin_amdgcn_cvt_pk_fp8_f32(v, v, 0, false);
  return (unsigned char)(p & 0xFF);
}
__device__ inline unsigned pk4_fp8(float a0, float a1, float a2, float a3) {
  int w0 = __builtin_amdgcn_cvt_pk_fp8_f32(a0, a1, 0, false);
  int w1 = __builtin_amdgcn_cvt_pk_fp8_f32(a2, a3, 0, false);
  return (unsigned)(w0 & 0xFFFF) | ((unsigned)(w1 & 0xFFFF) << 16);
}
__device__ inline void acc_fp8x4(unsigned w, float& a0, float& a1, float& a2, float& a3) {
  f32x2 lo = __builtin_amdgcn_cvt_pk_f32_fp8((int)w, false);
  f32x2 hi = __builtin_amdgcn_cvt_pk_f32_fp8((int)w, true);
  a0 += lo[0]; a1 += lo[1]; a2 += hi[0]; a3 += hi[1];
}

// ---------- argmax-key helpers ----------
__device__ inline unsigned ordered_bits(float f) {
  unsigned u = __float_as_uint(f);
  return (u & 0x80000000u) ? ~u : (u | 0x80000000u);
}
__device__ inline int key_idx(unsigned long long k) {
  return (int)(0xFFFFFFFFu - (unsigned)(k & 0xFFFFFFFFull));
}

// ---------- prep: bucket cursors + zero accum region + weight transpose-convert ----------
__global__ __launch_bounds__(256) void prep(uint4* __restrict__ zp, int n16, int* __restrict__ bcur, int zb,
                                            const float* __restrict__ W1, const float* __restrict__ W2,
                                            const float* __restrict__ W3, ushort* __restrict__ Wt) {
  int b = blockIdx.x, t = threadIdx.x;
  if (b == 0) { bcur[t] = t * BCAP; return; }
  if (b <= zb) {
    int i = (b - 1) * 256 + t;
    if (i < n16) zp[i] = make_uint4(0u, 0u, 0u, 0u);
    return;
  }
  int cb = b - zb - 1;                 // 0..191
  const float* W = (cb < 64) ? W1 : (cb < 128) ? W2 : W3;
  ushort* o = Wt + (size_t)(cb >> 6) * 128 * 128;
  int idx = (cb & 63) * 256 + t;
  int c = idx >> 7, k = idx & 127;
  o[idx] = f2bf(W[k * 128 + c]);
}

// ---------- pass C: bucket edges, packed u32 staged = (dl<<23)|src ----------
__global__ __launch_bounds__(256) void edge_bucket(const int* __restrict__ ei, int E, int nb,
                                                   int* __restrict__ bcur, unsigned* __restrict__ staged) {
  __shared__ unsigned spk[ECHUNK];
  __shared__ unsigned char sbk[ECHUNK];
  __shared__ int hist[NBMAX];
  __shared__ int cur[NBMAX];
  int t = threadIdx.x;
  int e0 = blockIdx.x * ECHUNK;
  int cnt = min(ECHUNK, E - e0);
  if (t < nb) hist[t] = 0;
  __syncthreads();
  for (int i = t; i < cnt; i += 256) {
    int s = ei[e0 + i];
    int d = ei[E + e0 + i];
    int b = d >> NB_SHIFT;
    spk[i] = ((unsigned)(d & ((1 << NB_SHIFT) - 1)) << 23) | (unsigned)s;
    sbk[i] = (unsigned char)b;
    atomicAdd(&hist[b], 1);
  }
  __syncthreads();
  if (t < nb) cur[t] = atomicAdd(&bcur[t], hist[t]);
  __syncthreads();
  for (int i = t; i < cnt; i += 256) {
    int b = sbk[i];
    int pos = atomicAdd(&cur[b], 1);
    staged[pos] = spk[i];
  }
}

// ---------- pass D: per-bucket degree count + scan + CSR fill (packed staged) ----------
__global__ __launch_bounds__(512) void bucket_csr2(const unsigned* __restrict__ staged, const int* __restrict__ bcur,
                                                   int* __restrict__ rows, int* __restrict__ cnt,
                                                   float* __restrict__ dinv, int* __restrict__ col, int n) {
  __shared__ int lcnt[512];
  __shared__ int lgs[512];
  __shared__ int lcur[512];
  __shared__ int lsc[512];
  int b = blockIdx.x;
  int t = threadIdx.x;
  int base = b << NB_SHIFT;
  lcnt[t] = 0;
  lcur[t] = 0;
  __syncthreads();
  int start = b * BCAP;
  int end = bcur[b];
  for (int i = start + t; i < end; i += 512) {
    atomicAdd(&lcnt[staged[i] >> 23], 1);
  }
  __syncthreads();
  int v = lcnt[t];
  lsc[t] = v;
  __syncthreads();
  for (int d = 1; d < 512; d <<= 1) {
    int x = (t >= d) ? lsc[t - d] : 0;
    __syncthreads();
    lsc[t] += x;
    __syncthreads();
  }
  int gstart = start + lsc[t] - v;
  lgs[t] = gstart;
  int node = base + t;
  if (node < n) {
    rows[node] = gstart;
    cnt[node] = v;
    dinv[node] = rsqrtf((float)v + 1.0f);
  }
  __syncthreads();
  for (int i = start + t; i < end; i += 512) {
    unsigned p = staged[i];
    int dl = (int)(p >> 23);
    int pos = atomicAdd(&lcur[dl], 1);
    col[lgs[dl] + pos] = (int)(p & 0x7FFFFFu);
  }
}

// ---------- MFMA GEMM (layer 1): hW8(fp8) = (x @ W1) * dinv[row] * 16 ----------
__global__ __launch_bounds__(256) void mfma_gemm(const float* __restrict__ Ain, const ushort* __restrict__ Wt,
                                                 const float* __restrict__ dinv, unsigned char* __restrict__ hW8, int n) {
  int w = threadIdx.x >> 6;
  int l = threadIdx.x & 63;
  int lr = l & 15;
  int lg = l >> 4;
  int r0 = blockIdx.x * 64 + w * 16;
  if (r0 >= n) return;
  int arow = r0 + lr;
  if (arow >= n) arow = n - 1;

  f32x4 acc[8];
#pragma unroll
  for (int ct = 0; ct < 8; ++ct) acc[ct] = (f32x4){0.f, 0.f, 0.f, 0.f};

#pragma unroll
  for (int kk = 0; kk < 4; ++kk) {
    const float* Af = Ain + (size_t)arow * 128 + kk * 32 + lg * 8;
    float4 f0 = ((const float4*)Af)[0];
    float4 f1 = ((const float4*)Af)[1];
    short8 a;
    a[0] = (short)f2bf(f0.x); a[1] = (short)f2bf(f0.y);
    a[2] = (short)f2bf(f0.z); a[3] = (short)f2bf(f0.w);
    a[4] = (short)f2bf(f1.x); a[5] = (short)f2bf(f1.y);
    a[6] = (short)f2bf(f1.z); a[7] = (short)f2bf(f1.w);
#pragma unroll
    for (int ct = 0; ct < 8; ++ct) {
      short8 bfrag = ((const short8*)(Wt + (size_t)(ct * 16 + lr) * 128))[kk * 4 + lg];
      acc[ct] = __builtin_amdgcn_mfma_f32_16x16x32_bf16(a, bfrag, acc[ct], 0, 0, 0);
    }
  }

#pragma unroll
  for (int r = 0; r < 4; ++r) {
    int row = r0 + lg * 4 + r;
    if (row < n) {
      float dv = dinv[row] * FP8_SCALE;
#pragma unroll
      for (int ct = 0; ct < 8; ++ct) {
        hW8[(size_t)row * 128 + ct * 16 + lr] = f2fp8(acc[ct][r] * dv);
      }
    }
  }
}

// ---------- GEMM layers 2/3: hW8out = (Hf8/16 @ W) * dinv[row] * 16  (A carries x16 already) ----------
__global__ __launch_bounds__(256) void gemm8(const unsigned char* __restrict__ Hf8, const ushort* __restrict__ Wt,
                                             const float* __restrict__ dinv, unsigned char* __restrict__ hW8, int n) {
  int w = threadIdx.x >> 6;
  int l = threadIdx.x & 63;
  int lr = l & 15;
  int lg = l >> 4;
  int r0 = blockIdx.x * 64 + w * 16;
  if (r0 >= n) return;
  int arow = r0 + lr;
  if (arow >= n) arow = n - 1;
  const uint2* Arow = (const uint2*)(Hf8 + (size_t)arow * 128);

  f32x4 acc[8];
#pragma unroll
  for (int ct = 0; ct < 8; ++ct) acc[ct] = (f32x4){0.f, 0.f, 0.f, 0.f};

#pragma unroll
  for (int kk = 0; kk < 4; ++kk) {
    uint2 a8 = Arow[kk * 4 + lg];
    f32x2 p0 = __builtin_amdgcn_cvt_pk_f32_fp8((int)a8.x, false);
    f32x2 p1 = __builtin_amdgcn_cvt_pk_f32_fp8((int)a8.x, true);
    f32x2 p2 = __builtin_amdgcn_cvt_pk_f32_fp8((int)a8.y, false);
    f32x2 p3 = __builtin_amdgcn_cvt_pk_f32_fp8((int)a8.y, true);
    short8 a;
    a[0] = (short)f2bf(p0[0]); a[1] = (short)f2bf(p0[1]);
    a[2] = (short)f2bf(p1[0]); a[3] = (short)f2bf(p1[1]);
    a[4] = (short)f2bf(p2[0]); a[5] = (short)f2bf(p2[1]);
    a[6] = (short)f2bf(p3[0]); a[7] = (short)f2bf(p3[1]);
#pragma unroll
    for (int ct = 0; ct < 8; ++ct) {
      short8 bfrag = ((const short8*)(Wt + (size_t)(ct * 16 + lr) * 128))[kk * 4 + lg];
      acc[ct] = __builtin_amdgcn_mfma_f32_16x16x32_bf16(a, bfrag, acc[ct], 0, 0, 0);
    }
  }

#pragma unroll
  for (int r = 0; r < 4; ++r) {
    int row = r0 + lg * 4 + r;
    if (row < n) {
      float dv = dinv[row];     // A already carries the x16 fp8 scale
#pragma unroll
      for (int ct = 0; ct < 8; ++ct) {
        hW8[(size_t)row * 128 + ct * 16 + lr] = f2fp8(acc[ct][r] * dv);
      }
    }
  }
}

// ---------- fused gather (fp8 rows, ILP-4, 256 thr / 8 nodes, no barrier) ----------
// H[g] = relu(dinv[g]/16*(hW8in[g] + sum hW8in[src]) + b); OUTFP8: store fp8(H*16), else bf16
template <int OUTFP8>
__global__ __launch_bounds__(256) void gather_k(const int* __restrict__ row_start, const int* __restrict__ cnt,
                                                const int* __restrict__ col, const unsigned char* __restrict__ hW8,
                                                const float* __restrict__ dinv, const float* __restrict__ bias,
                                                void* __restrict__ outp, int n) {
  int g = (blockIdx.x * 256 + threadIdx.x) >> 5;
  if (g >= n) return;
  int lane = threadIdx.x & 31;
  const unsigned* h32 = (const unsigned*)hW8;
  float a0 = 0.f, a1 = 0.f, a2 = 0.f, a3 = 0.f;
  acc_fp8x4(h32[(size_t)g * 32 + lane], a0, a1, a2, a3);
  int jb = row_start[g];
  int je = jb + cnt[g];
  int j = jb;
  for (; j + 4 <= je; j += 4) {
    int s0 = __builtin_nontemporal_load(col + j);
    int s1 = __builtin_nontemporal_load(col + j + 1);
    int s2 = __builtin_nontemporal_load(col + j + 2);
    int s3 = __builtin_nontemporal_load(col + j + 3);
    unsigned w0 = h32[(size_t)s0 * 32 + lane];
    unsigned w1 = h32[(size_t)s1 * 32 + lane];
    unsigned w2 = h32[(size_t)s2 * 32 + lane];
    unsigned w3 = h32[(size_t)s3 * 32 + lane];
    acc_fp8x4(w0, a0, a1, a2, a3);
    acc_fp8x4(w1, a0, a1, a2, a3);
    acc_fp8x4(w2, a0, a1, a2, a3);
    acc_fp8x4(w3, a0, a1, a2, a3);
  }
  for (; j < je; ++j) {
    int s0 = __builtin_nontemporal_load(col + j);
    unsigned w0 = h32[(size_t)s0 * 32 + lane];
    acc_fp8x4(w0, a0, a1, a2, a3);
  }
  float din = dinv[g] * FP8_INV_SCALE;
  float4 bb = ((const float4*)bias)[lane];
  a0 = fmaxf(fmaf(a0, din, bb.x), 0.f);
  a1 = fmaxf(fmaf(a1, din, bb.y), 0.f);
  a2 = fmaxf(fmaf(a2, din, bb.z), 0.f);
  a3 = fmaxf(fmaf(a3, din, bb.w), 0.f);
  if (OUTFP8) {
    unsigned wo = pk4_fp8(a0 * FP8_SCALE, a1 * FP8_SCALE, a2 * FP8_SCALE, a3 * FP8_SCALE);
    ((unsigned*)outp)[(size_t)g * 32 + lane] = wo;
  } else {
    ushort4 o = {f2bf(a0), f2bf(a1), f2bf(a2), f2bf(a3)};
    *(ushort4*)((ushort*)outp + (size_t)g * 128 + lane * 4) = o;
  }
}

// ---------- pooling (bf16 in, parallel, grid-stride over rows) ----------
#define POOL_GRID 512
__global__ __launch_bounds__(256) void pool_kernel(const ushort* __restrict__ gcn, float* __restrict__ psum,
                                                   float* __restrict__ pmax, int nrows) {
  __shared__ float ls[16 * 128];
  __shared__ float lm[16 * 128];
  int t = threadIdx.x;
  int g = t >> 4;
  int c = t & 15;
  float s0 = 0.f, s1 = 0.f, s2 = 0.f, s3 = 0.f, s4 = 0.f, s5 = 0.f, s6 = 0.f, s7 = 0.f;
  float m0 = 0.f, m1 = 0.f, m2 = 0.f, m3 = 0.f, m4 = 0.f, m5 = 0.f, m6 = 0.f, m7 = 0.f;
  for (int r = blockIdx.x * 16 + g; r < nrows; r += POOL_GRID * 16) {
    uint4 w = *(const uint4*)(gcn + (size_t)r * 128 + c * 8);
    float v0 = bflo(w.x), v1 = bfhi(w.x), v2 = bflo(w.y), v3 = bfhi(w.y);
    float v4 = bflo(w.z), v5 = bfhi(w.z), v6 = bflo(w.w), v7 = bfhi(w.w);
    s0 += v0; s1 += v1; s2 += v2; s3 += v3; s4 += v4; s5 += v5; s6 += v6; s7 += v7;
    m0 = fmaxf(m0, v0); m1 = fmaxf(m1, v1); m2 = fmaxf(m2, v2); m3 = fmaxf(m3, v3);
    m4 = fmaxf(m4, v4); m5 = fmaxf(m5, v5); m6 = fmaxf(m6, v6); m7 = fmaxf(m7, v7);
  }
  int cb = c * 8;
  ls[g * 128 + cb + 0] = s0; ls[g * 128 + cb + 1] = s1; ls[g * 128 + cb + 2] = s2; ls[g * 128 + cb + 3] = s3;
  ls[g * 128 + cb + 4] = s4; ls[g * 128 + cb + 5] = s5; ls[g * 128 + cb + 6] = s6; ls[g * 128 + cb + 7] = s7;
  lm[g * 128 + cb + 0] = m0; lm[g * 128 + cb + 1] = m1; lm[g * 128 + cb + 2] = m2; lm[g * 128 + cb + 3] = m3;
  lm[g * 128 + cb + 4] = m4; lm[g * 128 + cb + 5] = m5; lm[g * 128 + cb + 6] = m6; lm[g * 128 + cb + 7] = m7;
  __syncthreads();
  if (t < 128) {
    float s = 0.f, m = 0.f;
#pragma unroll
    for (int gg = 0; gg < 16; ++gg) {
      s += ls[gg * 128 + t];
      m = fmaxf(m, lm[gg * 128 + t]);
    }
    atomicAdd(&psum[t], s);
    atomicMax((unsigned*)&pmax[t], __float_as_uint(m));
  }
}

// ---------- fused head: 2 cols/thread GEMV + mask + gumbel + exp + sum + argmax ----------
__global__ __launch_bounds__(256) void head_fused(const float* __restrict__ W, const float* __restrict__ bias,
                                                  const float* __restrict__ g, const float* __restrict__ psum,
                                                  const float* __restrict__ pmax, float invn,
                                                  const int* __restrict__ conn, int use_conn,
                                                  float* __restrict__ ebuf, unsigned long long* __restrict__ cell,
                                                  float* __restrict__ sum, int maxn, int n) {
  __shared__ float p[256];
  __shared__ unsigned long long kred[256];
  __shared__ float sred[256];
  int t = threadIdx.x;
  p[t] = (t < 128) ? psum[t] * invn : pmax[t - 128];
  __syncthreads();
  int j0 = blockIdx.x * 512 + t;
  int j1 = j0 + 256;
  bool v0 = j0 < maxn, v1 = j1 < maxn;
  float acc0 = 0.f, acc1 = 0.f;
#pragma unroll 8
  for (int k = 0; k < 256; ++k) {
    const float* row = W + (size_t)k * maxn;
    float w0 = v0 ? __builtin_nontemporal_load(row + j0) : 0.f;
    float w1 = v1 ? __builtin_nontemporal_load(row + j1) : 0.f;
    acc0 = fmaf(p[k], w0, acc0);
    acc1 = fmaf(p[k], w1, acc1);
  }
  unsigned long long key = 0ull;
  float evs = 0.f;
  if (v0) {
    float logit = acc0 + bias[j0];
    if (j0 >= n) logit = MASKV;
    if (use_conn && conn[j0]) logit = MASKV;
    float zv = (logit + g[j0]) * INV_TAU;
    float ev = expf(zv);
    ebuf[j0] = ev;
    evs += ev;
    unsigned long long k0 = ((unsigned long long)ordered_bits(zv) << 32) | (unsigned long long)(0xFFFFFFFFu - (unsigned)j0);
    key = k0;
  }
  if (v1) {
    float logit = acc1 + bias[j1];
    if (j1 >= n) logit = MASKV;
    if (use_conn && conn[j1]) logit = MASKV;
    float zv = (logit + g[j1]) * INV_TAU;
    float ev = expf(zv);
    ebuf[j1] = ev;
    evs += ev;
    unsigned long long k1 = ((unsigned long long)ordered_bits(zv) << 32) | (unsigned long long)(0xFFFFFFFFu - (unsigned)j1);
    key = key > k1 ? key : k1;
  }
  kred[t] = key;
  sred[t] = evs;
  __syncthreads();
  for (int s = 128; s > 0; s >>= 1) {
    if (t < s) {
      kred[t] = kred[t] > kred[t + s] ? kred[t] : kred[t + s];
      sred[t] += sred[t + s];
    }
    __syncthreads();
  }
  if (t == 0) {
    atomicMax(cell, kred[0]);
    atomicAdd(sum, sred[0]);
  }
}

// ---------- connectivity mask ----------
__global__ __launch_bounds__(256) void conn_kernel(const int* __restrict__ ei, int E,
                                                   const unsigned long long* __restrict__ cell1,
                                                   int* __restrict__ conn) {
  int e = blockIdx.x * 256 + threadIdx.x;
  int i1 = key_idx(*cell1);
  if (e == 0) conn[i1] = 1;
  if (e < E) {
    int s = ei[e], d = ei[E + e];
    if (s == i1 || d == i1) {
      conn[s] = 1;
      conn[d] = 1;
    }
  }
}

// ---------- edge+stop head body (runs in last block of finish) ----------
__device__ void edge_stop(const ushort* __restrict__ gcn, const float* __restrict__ eW,
                          const float* __restrict__ ebias, const float* __restrict__ ge,
                          const unsigned long long* __restrict__ c1, const unsigned long long* __restrict__ c2,
                          float* __restrict__ ob) {
  __shared__ float red[3 * 128];
  int t = threadIdx.x;
  if (t < 128) {
    int i1 = key_idx(*c1);
    int i2 = key_idx(*c2);
    float ea  = __uint_as_float((unsigned)gcn[(size_t)i1 * HID + t] << 16);
    float eb2 = __uint_as_float((unsigned)gcn[(size_t)i2 * HID + t] << 16);
    red[t]       = ea * eW[t * 3 + 0] + eb2 * eW[(128 + t) * 3 + 0];
    red[128 + t] = ea * eW[t * 3 + 1] + eb2 * eW[(128 + t) * 3 + 1];
    red[256 + t] = ea * eW[t * 3 + 2] + eb2 * eW[(128 + t) * 3 + 2];
  }
  __syncthreads();
  for (int s = 64; s > 0; s >>= 1) {
    if (t < s) {
      red[t] += red[t + s];
      red[128 + t] += red[128 + t + s];
      red[256 + t] += red[256 + t + s];
    }
    __syncthreads();
  }
  if (t == 0) {
    float z0 = (red[0]   + ebias[0] + ge[0]) * INV_TAU;
    float z1 = (red[128] + ebias[1] + ge[1]) * INV_TAU;
    float z2 = (red[256] + ebias[2] + ge[2]) * INV_TAU;
    float m = fmaxf(z0, fmaxf(z1, z2));
    float e0 = expf(z0 - m), e1 = expf(z1 - m), e2 = expf(z2 - m);
    float inv = 1.f / (e0 + e1 + e2);
    ob[0] = e0 * inv;
    ob[1] = e1 * inv;
    ob[2] = e2 * inv;
    ob[3] = 1.0f;
  }
}

// ---------- finish: normalize both heads + edge/stop head (last block) ----------
__global__ __launch_bounds__(256) void finish(const float* __restrict__ e1, const float* __restrict__ s1,
                                              const float* __restrict__ e2, const float* __restrict__ s2,
                                              float* __restrict__ out, int maxn,
                                              const ushort* __restrict__ gcn, const float* __restrict__ eW,
                                              const float* __restrict__ ebias, const float* __restrict__ ge,
                                              const unsigned long long* __restrict__ c1,
                                              const unsigned long long* __restrict__ c2) {
  if (blockIdx.x == gridDim.x - 1) {
    edge_stop(gcn, eW, ebias, ge, c1, c2, out + 2 * (size_t)maxn);
    return;
  }
  int j = blockIdx.x * 256 + threadIdx.x;
  if (j < maxn) {
    out[j] = e1[j] / (*s1);
    out[maxn + j] = e2[j] / (*s2);
  }
}

// ---------- launch ----------
extern "C" void kernel_launch(void* const* d_in, const int* in_sizes, int n_in,
                              void* d_out, int out_size, void* d_ws, size_t ws_size,
                              hipStream_t stream) {
  const float* x  = (const float*)d_in[0];
  const int* ei   = (const int*)d_in[1];
  const float* W1 = (const float*)d_in[2];
  const float* b1 = (const float*)d_in[3];
  const float* W2 = (const float*)d_in[4];
  const float* b2 = (const float*)d_in[5];
  const float* W3 = (const float*)d_in[6];
  const float* b3 = (const float*)d_in[7];
  const float* n1W = (const float*)d_in[8];
  const float* n1b = (const float*)d_in[9];
  const float* n2W = (const float*)d_in[10];
  const float* n2b = (const float*)d_in[11];
  const float* eW  = (const float*)d_in[12];
  const float* eb  = (const float*)d_in[13];
  const float* g1  = (const float*)d_in[16];
  const float* g2  = (const float*)d_in[17];
  const float* ge  = (const float*)d_in[18];

  int n    = in_sizes[0] / HID;
  int E    = in_sizes[1] / 2;
  int maxn = in_sizes[9];
  int nb   = (n + (1 << NB_SHIFT) - 1) >> NB_SHIFT;
  float* out = (float*)d_out;

  char* ws = (char*)d_ws;
  size_t o = 0;
  unsigned char* HW8A = (unsigned char*)(ws + o); o += (size_t)n * HID;   // fp8 hW ping
  unsigned char* HW8B = (unsigned char*)(ws + o); o += (size_t)n * HID;   // fp8 hW pong
  unsigned char* HF8  = (unsigned char*)(ws + o); o += (size_t)n * HID;   // fp8 H (gather out)
  ushort* GCN = (ushort*)(ws + o); o += (size_t)n * HID * 2;              // layer-3 out bf16
  ushort* WT  = (ushort*)(ws + o); o += (size_t)3 * 128 * 128 * 2;
  float* EB1  = (float*)(ws + o);  o += (size_t)maxn * 4;
  float* EB2  = (float*)(ws + o);  o += (size_t)maxn * 4;
  int* ROWS   = (int*)(ws + o);    o += (size_t)n * 4;
  int* CNT    = (int*)(ws + o);    o += (size_t)n * 4;
  int* COL    = (int*)(ws + o);    o += (size_t)NBMAX * BCAP * 4;         // bucket-local CSR cols
  unsigned* STAGED = (unsigned*)(ws + o); o += (size_t)NBMAX * BCAP * 4;  // packed (dl<<23)|src
  float* DINV = (float*)(ws + o);  o += (size_t)n * 4;
  int* BCUR   = (int*)(ws + o);    o += 1024;
  // ---- zeroed region (16B aligned; zeroed by prep) ----
  char* zero_start = ws + o;
  int* CONN   = (int*)(ws + o);    o += (size_t)maxn * 4;
  float* PS   = (float*)(ws + o);  o += 128 * 4;
  float* PM   = (float*)(ws + o);  o += 128 * 4;
  unsigned long long* CELLS = (unsigned long long*)(ws + o);
  float* SUM1 = (float*)(ws + o + 16);
  float* SUM2 = (float*)(ws + o + 20);
  o += 64;
  size_t zero_bytes = (size_t)((ws + o) - zero_start);
  int zero16 = (int)(zero_bytes / 16);
  int zb = (zero16 + 255) / 256;

  dim3 blk(256);
  int gE = (E + 255) / 256;
  int gHeadHalf = (maxn + 511) / 512;
  int gNorm = (maxn + 255) / 256;
  int gGemm = (n + 63) / 64;
  int gGather = (int)(((size_t)n * 32 + 255) / 256);
  int gEB = (E + ECHUNK - 1) / ECHUNK;
  float invn = 1.0f / (float)n;

  // prep: bcur init + zero accum region + weight cvt
  prep<<<1 + zb + 192, blk, 0, stream>>>((uint4*)zero_start, zero16, BCUR, zb, W1, W2, W3, WT);

  // locality-preserving CSR build (fixed-cap buckets, packed staging)
  edge_bucket<<<gEB, blk, 0, stream>>>(ei, E, nb, BCUR, STAGED);
  bucket_csr2<<<nb, dim3(512), 0, stream>>>(STAGED, BCUR, ROWS, CNT, DINV, COL, n);

  // layer 1 GEMM: x (fp32) -> HW8A
  mfma_gemm<<<gGemm, blk, 0, stream>>>(x, WT, DINV, HW8A, n);
  // gather1 (fp8 out): HW8A -> HF8
  gather_k<1><<<gGather, blk, 0, stream>>>(ROWS, CNT, COL, HW8A, DINV, b1, HF8, n);
  // layer 2 GEMM (fp8 in): HF8 -> HW8B
  gemm8<<<gGemm, blk, 0, stream>>>(HF8, WT + 128 * 128, DINV, HW8B, n);
  // gather2 (fp8 out): HW8B -> HF8
  gather_k<1><<<gGather, blk, 0, stream>>>(ROWS, CNT, COL, HW8B, DINV, b2, HF8, n);
  // layer 3 GEMM (fp8 in): HF8 -> HW8A
  gemm8<<<gGemm, blk, 0, stream>>>(HF8, WT + 2 * 128 * 128, DINV, HW8A, n);
  // gather3 (bf16 out): HW8A -> GCN
  gather_k<0><<<gGather, blk, 0, stream>>>(ROWS, CNT, COL, HW8A, DINV, b3, GCN, n);

  // pool partials
  pool_kernel<<<POOL_GRID, blk, 0, stream>>>(GCN, PS, PM, n);

  // head 1 (pool finalized inline; exp+sum+argmax fused; 2 cols/thread)
  head_fused<<<gHeadHalf, blk, 0, stream>>>(n1W, n1b, g1, PS, PM, invn, nullptr, 0, EB1, &CELLS[0], SUM1, maxn, n);

  // conn mask from i1
  conn_kernel<<<gE, blk, 0, stream>>>(ei, E, &CELLS[0], CONN);

  // head 2
  head_fused<<<gHeadHalf, blk, 0, stream>>>(n2W, n2b, g2, PS, PM, invn, CONN, 1, EB2, &CELLS[1], SUM2, maxn, n);

  // normalize both heads + edge/stop head
  finish<<<gNorm + 1, blk, 0, stream>>>(EB1, SUM1, EB2, SUM2, out, maxn, GCN, eW, eb, ge, &CELLS[0], &CELLS[1]);
}

// Round 17
// 391.186 us; speedup vs baseline: 1.0222x; 1.0222x over previous
//
#include <hip/hip_runtime.h>

#define HID 128
#define MASKV -1000000000.0f
#define INV_TAU 2.0f
#define NB_SHIFT 9          // bucket = dst >> 9 (512 nodes/bucket)
#define NBMAX 256
#define ECHUNK 4096
#define BCAP 10240          // fixed per-bucket capacity (mean ~8163, >20 sigma headroom)
#define FP8_SCALE 16.0f
#define FP8_INV_SCALE 0.0625f

using short8 = __attribute__((ext_vector_type(8))) short;
using f32x4  = __attribute__((ext_vector_type(4))) float;
using f32x2  = __attribute__((ext_vector_type(2))) float;

// ---------- bf16 helpers ----------
__device__ inline ushort f2bf(float f) {
  unsigned u = __float_as_uint(f);
  return (ushort)((u + 0x7FFFu + ((u >> 16) & 1u)) >> 16);
}
__device__ inline float bflo(unsigned u) { return __uint_as_float(u << 16); }
__device__ inline float bfhi(unsigned u) { return __uint_as_float(u & 0xFFFF0000u); }

// ---------- fp8 e4m3 helpers (HW cvt) ----------
__device__ inline unsigned char f2fp8(float v) {
  int p = __builtin_amdgcn_cvt_pk_fp8_f32(v, v, 0, false);
  return (unsigned char)(p & 0xFF);
}
__device__ inline void acc_fp8x4(unsigned w, float& a0, float& a1, float& a2, float& a3) {
  f32x2 lo = __builtin_amdgcn_cvt_pk_f32_fp8((int)w, false);
  f32x2 hi = __builtin_amdgcn_cvt_pk_f32_fp8((int)w, true);
  a0 += lo[0]; a1 += lo[1]; a2 += hi[0]; a3 += hi[1];
}

// ---------- argmax-key helpers ----------
__device__ inline unsigned ordered_bits(float f) {
  unsigned u = __float_as_uint(f);
  return (u & 0x80000000u) ? ~u : (u | 0x80000000u);
}
__device__ inline int key_idx(unsigned long long k) {
  return (int)(0xFFFFFFFFu - (unsigned)(k & 0xFFFFFFFFull));
}

// ---------- prep: bucket cursors + zero accum region + weight transpose-convert ----------
__global__ __launch_bounds__(256) void prep(uint4* __restrict__ zp, int n16, int* __restrict__ bcur, int zb,
                                            const float* __restrict__ W1, const float* __restrict__ W2,
                                            const float* __restrict__ W3, ushort* __restrict__ Wt) {
  int b = blockIdx.x, t = threadIdx.x;
  if (b == 0) { bcur[t] = t * BCAP; return; }
  if (b <= zb) {
    int i = (b - 1) * 256 + t;
    if (i < n16) zp[i] = make_uint4(0u, 0u, 0u, 0u);
    return;
  }
  int cb = b - zb - 1;                 // 0..191
  const float* W = (cb < 64) ? W1 : (cb < 128) ? W2 : W3;
  ushort* o = Wt + (size_t)(cb >> 6) * 128 * 128;
  int idx = (cb & 63) * 256 + t;
  int c = idx >> 7, k = idx & 127;
  o[idx] = f2bf(W[k * 128 + c]);
}

// ---------- pass C: bucket edges, packed u32 staged = (dl<<23)|src ----------
__global__ __launch_bounds__(256) void edge_bucket(const int* __restrict__ ei, int E, int nb,
                                                   int* __restrict__ bcur, unsigned* __restrict__ staged) {
  __shared__ unsigned spk[ECHUNK];
  __shared__ unsigned char sbk[ECHUNK];
  __shared__ int hist[NBMAX];
  __shared__ int cur[NBMAX];
  int t = threadIdx.x;
  int e0 = blockIdx.x * ECHUNK;
  int cnt = min(ECHUNK, E - e0);
  if (t < nb) hist[t] = 0;
  __syncthreads();
  for (int i = t; i < cnt; i += 256) {
    int s = ei[e0 + i];
    int d = ei[E + e0 + i];
    int b = d >> NB_SHIFT;
    spk[i] = ((unsigned)(d & ((1 << NB_SHIFT) - 1)) << 23) | (unsigned)s;
    sbk[i] = (unsigned char)b;
    atomicAdd(&hist[b], 1);
  }
  __syncthreads();
  if (t < nb) cur[t] = atomicAdd(&bcur[t], hist[t]);
  __syncthreads();
  for (int i = t; i < cnt; i += 256) {
    int b = sbk[i];
    int pos = atomicAdd(&cur[b], 1);
    staged[pos] = spk[i];
  }
}

// ---------- pass D: per-bucket degree count + scan + CSR fill (packed staged) ----------
__global__ __launch_bounds__(512) void bucket_csr2(const unsigned* __restrict__ staged, const int* __restrict__ bcur,
                                                   int* __restrict__ rows, int* __restrict__ cnt,
                                                   float* __restrict__ dinv, int* __restrict__ col, int n) {
  __shared__ int lcnt[512];
  __shared__ int lgs[512];
  __shared__ int lcur[512];
  __shared__ int lsc[512];
  int b = blockIdx.x;
  int t = threadIdx.x;
  int base = b << NB_SHIFT;
  lcnt[t] = 0;
  lcur[t] = 0;
  __syncthreads();
  int start = b * BCAP;
  int end = bcur[b];
  for (int i = start + t; i < end; i += 512) {
    atomicAdd(&lcnt[staged[i] >> 23], 1);
  }
  __syncthreads();
  int v = lcnt[t];
  lsc[t] = v;
  __syncthreads();
  for (int d = 1; d < 512; d <<= 1) {
    int x = (t >= d) ? lsc[t - d] : 0;
    __syncthreads();
    lsc[t] += x;
    __syncthreads();
  }
  int gstart = start + lsc[t] - v;
  lgs[t] = gstart;
  int node = base + t;
  if (node < n) {
    rows[node] = gstart;
    cnt[node] = v;
    dinv[node] = rsqrtf((float)v + 1.0f);
  }
  __syncthreads();
  for (int i = start + t; i < end; i += 512) {
    unsigned p = staged[i];
    int dl = (int)(p >> 23);
    int pos = atomicAdd(&lcur[dl], 1);
    col[lgs[dl] + pos] = (int)(p & 0x7FFFFFu);
  }
}

// ---------- MFMA GEMM (layer 1): hW8(fp8) = (x @ W1) * dinv[row] * 16 ----------
__global__ __launch_bounds__(256) void mfma_gemm(const float* __restrict__ Ain, const ushort* __restrict__ Wt,
                                                 const float* __restrict__ dinv, unsigned char* __restrict__ hW8, int n) {
  int w = threadIdx.x >> 6;
  int l = threadIdx.x & 63;
  int lr = l & 15;
  int lg = l >> 4;
  int r0 = blockIdx.x * 64 + w * 16;
  if (r0 >= n) return;
  int arow = r0 + lr;
  if (arow >= n) arow = n - 1;

  f32x4 acc[8];
#pragma unroll
  for (int ct = 0; ct < 8; ++ct) acc[ct] = (f32x4){0.f, 0.f, 0.f, 0.f};

#pragma unroll
  for (int kk = 0; kk < 4; ++kk) {
    const float* Af = Ain + (size_t)arow * 128 + kk * 32 + lg * 8;
    float4 f0 = ((const float4*)Af)[0];
    float4 f1 = ((const float4*)Af)[1];
    short8 a;
    a[0] = (short)f2bf(f0.x); a[1] = (short)f2bf(f0.y);
    a[2] = (short)f2bf(f0.z); a[3] = (short)f2bf(f0.w);
    a[4] = (short)f2bf(f1.x); a[5] = (short)f2bf(f1.y);
    a[6] = (short)f2bf(f1.z); a[7] = (short)f2bf(f1.w);
#pragma unroll
    for (int ct = 0; ct < 8; ++ct) {
      short8 bfrag = ((const short8*)(Wt + (size_t)(ct * 16 + lr) * 128))[kk * 4 + lg];
      acc[ct] = __builtin_amdgcn_mfma_f32_16x16x32_bf16(a, bfrag, acc[ct], 0, 0, 0);
    }
  }

#pragma unroll
  for (int r = 0; r < 4; ++r) {
    int row = r0 + lg * 4 + r;
    if (row < n) {
      float dv = dinv[row] * FP8_SCALE;
#pragma unroll
      for (int ct = 0; ct < 8; ++ct) {
        hW8[(size_t)row * 128 + ct * 16 + lr] = f2fp8(acc[ct][r] * dv);
      }
    }
  }
}

// ---------- fused gather + next-layer GEMM (layers 1->2, 2->3): 512 thr = 16 nodes/block ----------
// H[g] = relu(dinv[g]/16*(hW8in[g] + sum hW8in[src]) + b); hW8out[row] = (H @ Wt_next)*dinv[row]*16
__global__ __launch_bounds__(512) void gather_fuse(const int* __restrict__ row_start, const int* __restrict__ cnt,
                                                   const int* __restrict__ col, const unsigned char* __restrict__ hW8in,
                                                   const float* __restrict__ dinv, const float* __restrict__ bias,
                                                   const ushort* __restrict__ Wt_next, unsigned char* __restrict__ hW8out,
                                                   int n) {
  __shared__ ushort lh[16][136];   // +8 pad -> 2-way LDS conflicts only
  int t = threadIdx.x;
  int grp = t >> 5, lane = t & 31;
  int g = blockIdx.x * 16 + grp;
  bool valid = g < n;
  int gc = valid ? g : (n - 1);
  const unsigned* h32 = (const unsigned*)hW8in;
  float a0 = 0.f, a1 = 0.f, a2 = 0.f, a3 = 0.f;
  acc_fp8x4(h32[(size_t)gc * 32 + lane], a0, a1, a2, a3);
  int jb = row_start[gc];
  int je = jb + cnt[gc];
  int j = jb;
  for (; j + 4 <= je; j += 4) {
    int s0 = __builtin_nontemporal_load(col + j);
    int s1 = __builtin_nontemporal_load(col + j + 1);
    int s2 = __builtin_nontemporal_load(col + j + 2);
    int s3 = __builtin_nontemporal_load(col + j + 3);
    unsigned w0 = h32[(size_t)s0 * 32 + lane];
    unsigned w1 = h32[(size_t)s1 * 32 + lane];
    unsigned w2 = h32[(size_t)s2 * 32 + lane];
    unsigned w3 = h32[(size_t)s3 * 32 + lane];
    acc_fp8x4(w0, a0, a1, a2, a3);
    acc_fp8x4(w1, a0, a1, a2, a3);
    acc_fp8x4(w2, a0, a1, a2, a3);
    acc_fp8x4(w3, a0, a1, a2, a3);
  }
  for (; j < je; ++j) {
    int s0 = __builtin_nontemporal_load(col + j);
    unsigned w0 = h32[(size_t)s0 * 32 + lane];
    acc_fp8x4(w0, a0, a1, a2, a3);
  }
  float din = dinv[gc] * FP8_INV_SCALE;
  float4 bb = ((const float4*)bias)[lane];
  a0 = fmaxf(fmaf(a0, din, bb.x), 0.f);
  a1 = fmaxf(fmaf(a1, din, bb.y), 0.f);
  a2 = fmaxf(fmaf(a2, din, bb.z), 0.f);
  a3 = fmaxf(fmaf(a3, din, bb.w), 0.f);
  if (!valid) { a0 = a1 = a2 = a3 = 0.f; }

  ushort* dl = &lh[grp][lane * 4];
  dl[0] = f2bf(a0); dl[1] = f2bf(a1); dl[2] = f2bf(a2); dl[3] = f2bf(a3);
  __syncthreads();
  int w = t >> 6;            // wave -> column tile ct
  int l = t & 63;
  int lr = l & 15, lg = l >> 4;
  f32x4 acc = (f32x4){0.f, 0.f, 0.f, 0.f};
#pragma unroll
  for (int kk = 0; kk < 4; ++kk) {
    short8 a = *(const short8*)(&lh[lr][kk * 32 + lg * 8]);
    short8 bfrag = ((const short8*)(Wt_next + (size_t)(w * 16 + lr) * 128))[kk * 4 + lg];
    acc = __builtin_amdgcn_mfma_f32_16x16x32_bf16(a, bfrag, acc, 0, 0, 0);
  }
  int r0 = blockIdx.x * 16;
#pragma unroll
  for (int r = 0; r < 4; ++r) {
    int row = r0 + lg * 4 + r;
    if (row < n) {
      float dv = dinv[row] * FP8_SCALE;
      hW8out[(size_t)row * 128 + w * 16 + lr] = f2fp8(acc[r] * dv);
    }
  }
}

// ---------- layer-3 gather (256 thr / 8 nodes, no barrier, bf16 out) ----------
__global__ __launch_bounds__(256) void gather_k(const int* __restrict__ row_start, const int* __restrict__ cnt,
                                                const int* __restrict__ col, const unsigned char* __restrict__ hW8,
                                                const float* __restrict__ dinv, const float* __restrict__ bias,
                                                ushort* __restrict__ outp, int n) {
  int g = (blockIdx.x * 256 + threadIdx.x) >> 5;
  if (g >= n) return;
  int lane = threadIdx.x & 31;
  const unsigned* h32 = (const unsigned*)hW8;
  float a0 = 0.f, a1 = 0.f, a2 = 0.f, a3 = 0.f;
  acc_fp8x4(h32[(size_t)g * 32 + lane], a0, a1, a2, a3);
  int jb = row_start[g];
  int je = jb + cnt[g];
  int j = jb;
  for (; j + 4 <= je; j += 4) {
    int s0 = __builtin_nontemporal_load(col + j);
    int s1 = __builtin_nontemporal_load(col + j + 1);
    int s2 = __builtin_nontemporal_load(col + j + 2);
    int s3 = __builtin_nontemporal_load(col + j + 3);
    unsigned w0 = h32[(size_t)s0 * 32 + lane];
    unsigned w1 = h32[(size_t)s1 * 32 + lane];
    unsigned w2 = h32[(size_t)s2 * 32 + lane];
    unsigned w3 = h32[(size_t)s3 * 32 + lane];
    acc_fp8x4(w0, a0, a1, a2, a3);
    acc_fp8x4(w1, a0, a1, a2, a3);
    acc_fp8x4(w2, a0, a1, a2, a3);
    acc_fp8x4(w3, a0, a1, a2, a3);
  }
  for (; j < je; ++j) {
    int s0 = __builtin_nontemporal_load(col + j);
    unsigned w0 = h32[(size_t)s0 * 32 + lane];
    acc_fp8x4(w0, a0, a1, a2, a3);
  }
  float din = dinv[g] * FP8_INV_SCALE;
  float4 bb = ((const float4*)bias)[lane];
  a0 = fmaxf(fmaf(a0, din, bb.x), 0.f);
  a1 = fmaxf(fmaf(a1, din, bb.y), 0.f);
  a2 = fmaxf(fmaf(a2, din, bb.z), 0.f);
  a3 = fmaxf(fmaf(a3, din, bb.w), 0.f);
  ushort4 o = {f2bf(a0), f2bf(a1), f2bf(a2), f2bf(a3)};
  *(ushort4*)(outp + (size_t)g * 128 + lane * 4) = o;
}

// ---------- pooling (bf16 in, parallel, grid-stride over rows) ----------
#define POOL_GRID 512
__global__ __launch_bounds__(256) void pool_kernel(const ushort* __restrict__ gcn, float* __restrict__ psum,
                                                   float* __restrict__ pmax, int nrows) {
  __shared__ float ls[16 * 128];
  __shared__ float lm[16 * 128];
  int t = threadIdx.x;
  int g = t >> 4;
  int c = t & 15;
  float s0 = 0.f, s1 = 0.f, s2 = 0.f, s3 = 0.f, s4 = 0.f, s5 = 0.f, s6 = 0.f, s7 = 0.f;
  float m0 = 0.f, m1 = 0.f, m2 = 0.f, m3 = 0.f, m4 = 0.f, m5 = 0.f, m6 = 0.f, m7 = 0.f;
  for (int r = blockIdx.x * 16 + g; r < nrows; r += POOL_GRID * 16) {
    uint4 w = *(const uint4*)(gcn + (size_t)r * 128 + c * 8);
    float v0 = bflo(w.x), v1 = bfhi(w.x), v2 = bflo(w.y), v3 = bfhi(w.y);
    float v4 = bflo(w.z), v5 = bfhi(w.z), v6 = bflo(w.w), v7 = bfhi(w.w);
    s0 += v0; s1 += v1; s2 += v2; s3 += v3; s4 += v4; s5 += v5; s6 += v6; s7 += v7;
    m0 = fmaxf(m0, v0); m1 = fmaxf(m1, v1); m2 = fmaxf(m2, v2); m3 = fmaxf(m3, v3);
    m4 = fmaxf(m4, v4); m5 = fmaxf(m5, v5); m6 = fmaxf(m6, v6); m7 = fmaxf(m7, v7);
  }
  int cb = c * 8;
  ls[g * 128 + cb + 0] = s0; ls[g * 128 + cb + 1] = s1; ls[g * 128 + cb + 2] = s2; ls[g * 128 + cb + 3] = s3;
  ls[g * 128 + cb + 4] = s4; ls[g * 128 + cb + 5] = s5; ls[g * 128 + cb + 6] = s6; ls[g * 128 + cb + 7] = s7;
  lm[g * 128 + cb + 0] = m0; lm[g * 128 + cb + 1] = m1; lm[g * 128 + cb + 2] = m2; lm[g * 128 + cb + 3] = m3;
  lm[g * 128 + cb + 4] = m4; lm[g * 128 + cb + 5] = m5; lm[g * 128 + cb + 6] = m6; lm[g * 128 + cb + 7] = m7;
  __syncthreads();
  if (t < 128) {
    float s = 0.f, m = 0.f;
#pragma unroll
    for (int gg = 0; gg < 16; ++gg) {
      s += ls[gg * 128 + t];
      m = fmaxf(m, lm[gg * 128 + t]);
    }
    atomicAdd(&psum[t], s);
    atomicMax((unsigned*)&pmax[t], __float_as_uint(m));
  }
}

// ---------- fused head: 2 cols/thread GEMV + mask + gumbel + exp + sum + argmax ----------
__global__ __launch_bounds__(256) void head_fused(const float* __restrict__ W, const float* __restrict__ bias,
                                                  const float* __restrict__ g, const float* __restrict__ psum,
                                                  const float* __restrict__ pmax, float invn,
                                                  const int* __restrict__ conn, int use_conn,
                                                  float* __restrict__ ebuf, unsigned long long* __restrict__ cell,
                                                  float* __restrict__ sum, int maxn, int n) {
  __shared__ float p[256];
  __shared__ unsigned long long kred[256];
  __shared__ float sred[256];
  int t = threadIdx.x;
  p[t] = (t < 128) ? psum[t] * invn : pmax[t - 128];
  __syncthreads();
  int j0 = blockIdx.x * 512 + t;
  int j1 = j0 + 256;
  bool v0 = j0 < maxn, v1 = j1 < maxn;
  float acc0 = 0.f, acc1 = 0.f;
#pragma unroll 8
  for (int k = 0; k < 256; ++k) {
    const float* row = W + (size_t)k * maxn;
    float w0 = v0 ? __builtin_nontemporal_load(row + j0) : 0.f;
    float w1 = v1 ? __builtin_nontemporal_load(row + j1) : 0.f;
    acc0 = fmaf(p[k], w0, acc0);
    acc1 = fmaf(p[k], w1, acc1);
  }
  unsigned long long key = 0ull;
  float evs = 0.f;
  if (v0) {
    float logit = acc0 + bias[j0];
    if (j0 >= n) logit = MASKV;
    if (use_conn && conn[j0]) logit = MASKV;
    float zv = (logit + g[j0]) * INV_TAU;
    float ev = expf(zv);
    ebuf[j0] = ev;
    evs += ev;
    unsigned long long k0 = ((unsigned long long)ordered_bits(zv) << 32) | (unsigned long long)(0xFFFFFFFFu - (unsigned)j0);
    key = k0;
  }
  if (v1) {
    float logit = acc1 + bias[j1];
    if (j1 >= n) logit = MASKV;
    if (use_conn && conn[j1]) logit = MASKV;
    float zv = (logit + g[j1]) * INV_TAU;
    float ev = expf(zv);
    ebuf[j1] = ev;
    evs += ev;
    unsigned long long k1 = ((unsigned long long)ordered_bits(zv) << 32) | (unsigned long long)(0xFFFFFFFFu - (unsigned)j1);
    key = key > k1 ? key : k1;
  }
  kred[t] = key;
  sred[t] = evs;
  __syncthreads();
  for (int s = 128; s > 0; s >>= 1) {
    if (t < s) {
      kred[t] = kred[t] > kred[t + s] ? kred[t] : kred[t + s];
      sred[t] += sred[t + s];
    }
    __syncthreads();
  }
  if (t == 0) {
    atomicMax(cell, kred[0]);
    atomicAdd(sum, sred[0]);
  }
}

// ---------- connectivity mask ----------
__global__ __launch_bounds__(256) void conn_kernel(const int* __restrict__ ei, int E,
                                                   const unsigned long long* __restrict__ cell1,
                                                   int* __restrict__ conn) {
  int e = blockIdx.x * 256 + threadIdx.x;
  int i1 = key_idx(*cell1);
  if (e == 0) conn[i1] = 1;
  if (e < E) {
    int s = ei[e], d = ei[E + e];
    if (s == i1 || d == i1) {
      conn[s] = 1;
      conn[d] = 1;
    }
  }
}

// ---------- edge+stop head body (runs in last block of finish) ----------
__device__ void edge_stop(const ushort* __restrict__ gcn, const float* __restrict__ eW,
                          const float* __restrict__ ebias, const float* __restrict__ ge,
                          const unsigned long long* __restrict__ c1, const unsigned long long* __restrict__ c2,
                          float* __restrict__ ob) {
  __shared__ float red[3 * 128];
  int t = threadIdx.x;
  if (t < 128) {
    int i1 = key_idx(*c1);
    int i2 = key_idx(*c2);
    float ea  = __uint_as_float((unsigned)gcn[(size_t)i1 * HID + t] << 16);
    float eb2 = __uint_as_float((unsigned)gcn[(size_t)i2 * HID + t] << 16);
    red[t]       = ea * eW[t * 3 + 0] + eb2 * eW[(128 + t) * 3 + 0];
    red[128 + t] = ea * eW[t * 3 + 1] + eb2 * eW[(128 + t) * 3 + 1];
    red[256 + t] = ea * eW[t * 3 + 2] + eb2 * eW[(128 + t) * 3 + 2];
  }
  __syncthreads();
  for (int s = 64; s > 0; s >>= 1) {
    if (t < s) {
      red[t] += red[t + s];
      red[128 + t] += red[128 + t + s];
      red[256 + t] += red[256 + t + s];
    }
    __syncthreads();
  }
  if (t == 0) {
    float z0 = (red[0]   + ebias[0] + ge[0]) * INV_TAU;
    float z1 = (red[128] + ebias[1] + ge[1]) * INV_TAU;
    float z2 = (red[256] + ebias[2] + ge[2]) * INV_TAU;
    float m = fmaxf(z0, fmaxf(z1, z2));
    float e0 = expf(z0 - m), e1 = expf(z1 - m), e2 = expf(z2 - m);
    float inv = 1.f / (e0 + e1 + e2);
    ob[0] = e0 * inv;
    ob[1] = e1 * inv;
    ob[2] = e2 * inv;
    ob[3] = 1.0f;
  }
}

// ---------- finish: normalize both heads + edge/stop head (last block) ----------
__global__ __launch_bounds__(256) void finish(const float* __restrict__ e1, const float* __restrict__ s1,
                                              const float* __restrict__ e2, const float* __restrict__ s2,
                                              float* __restrict__ out, int maxn,
                                              const ushort* __restrict__ gcn, const float* __restrict__ eW,
                                              const float* __restrict__ ebias, const float* __restrict__ ge,
                                              const unsigned long long* __restrict__ c1,
                                              const unsigned long long* __restrict__ c2) {
  if (blockIdx.x == gridDim.x - 1) {
    edge_stop(gcn, eW, ebias, ge, c1, c2, out + 2 * (size_t)maxn);
    return;
  }
  int j = blockIdx.x * 256 + threadIdx.x;
  if (j < maxn) {
    out[j] = e1[j] / (*s1);
    out[maxn + j] = e2[j] / (*s2);
  }
}

// ---------- launch ----------
extern "C" void kernel_launch(void* const* d_in, const int* in_sizes, int n_in,
                              void* d_out, int out_size, void* d_ws, size_t ws_size,
                              hipStream_t stream) {
  const float* x  = (const float*)d_in[0];
  const int* ei   = (const int*)d_in[1];
  const float* W1 = (const float*)d_in[2];
  const float* b1 = (const float*)d_in[3];
  const float* W2 = (const float*)d_in[4];
  const float* b2 = (const float*)d_in[5];
  const float* W3 = (const float*)d_in[6];
  const float* b3 = (const float*)d_in[7];
  const float* n1W = (const float*)d_in[8];
  const float* n1b = (const float*)d_in[9];
  const float* n2W = (const float*)d_in[10];
  const float* n2b = (const float*)d_in[11];
  const float* eW  = (const float*)d_in[12];
  const float* eb  = (const float*)d_in[13];
  const float* g1  = (const float*)d_in[16];
  const float* g2  = (const float*)d_in[17];
  const float* ge  = (const float*)d_in[18];

  int n    = in_sizes[0] / HID;
  int E    = in_sizes[1] / 2;
  int maxn = in_sizes[9];
  int nb   = (n + (1 << NB_SHIFT) - 1) >> NB_SHIFT;
  float* out = (float*)d_out;

  char* ws = (char*)d_ws;
  size_t o = 0;
  unsigned char* HW8A = (unsigned char*)(ws + o); o += (size_t)n * HID;   // fp8 ping
  unsigned char* HW8B = (unsigned char*)(ws + o); o += (size_t)n * HID;   // fp8 pong
  ushort* GCN = (ushort*)(ws + o); o += (size_t)n * HID * 2;              // layer-3 out bf16
  ushort* WT  = (ushort*)(ws + o); o += (size_t)3 * 128 * 128 * 2;
  float* EB1  = (float*)(ws + o);  o += (size_t)maxn * 4;
  float* EB2  = (float*)(ws + o);  o += (size_t)maxn * 4;
  int* ROWS   = (int*)(ws + o);    o += (size_t)n * 4;
  int* CNT    = (int*)(ws + o);    o += (size_t)n * 4;
  int* COL    = (int*)(ws + o);    o += (size_t)NBMAX * BCAP * 4;         // bucket-local CSR cols
  unsigned* STAGED = (unsigned*)(ws + o); o += (size_t)NBMAX * BCAP * 4;  // packed (dl<<23)|src
  float* DINV = (float*)(ws + o);  o += (size_t)n * 4;
  int* BCUR   = (int*)(ws + o);    o += 1024;
  // ---- zeroed region (16B aligned; zeroed by prep) ----
  char* zero_start = ws + o;
  int* CONN   = (int*)(ws + o);    o += (size_t)maxn * 4;
  float* PS   = (float*)(ws + o);  o += 128 * 4;
  float* PM   = (float*)(ws + o);  o += 128 * 4;
  unsigned long long* CELLS = (unsigned long long*)(ws + o);
  float* SUM1 = (float*)(ws + o + 16);
  float* SUM2 = (float*)(ws + o + 20);
  o += 64;
  size_t zero_bytes = (size_t)((ws + o) - zero_start);
  int zero16 = (int)(zero_bytes / 16);
  int zb = (zero16 + 255) / 256;

  dim3 blk(256);
  int gE = (E + 255) / 256;
  int gHeadHalf = (maxn + 511) / 512;
  int gNorm = (maxn + 255) / 256;
  int gGemm = (n + 63) / 64;
  int gFuse = (n + 15) / 16;
  int gGather = (int)(((size_t)n * 32 + 255) / 256);
  int gEB = (E + ECHUNK - 1) / ECHUNK;
  float invn = 1.0f / (float)n;

  // prep: bcur init + zero accum region + weight cvt
  prep<<<1 + zb + 192, blk, 0, stream>>>((uint4*)zero_start, zero16, BCUR, zb, W1, W2, W3, WT);

  // locality-preserving CSR build (fixed-cap buckets, packed staging)
  edge_bucket<<<gEB, blk, 0, stream>>>(ei, E, nb, BCUR, STAGED);
  bucket_csr2<<<nb, dim3(512), 0, stream>>>(STAGED, BCUR, ROWS, CNT, DINV, COL, n);

  // layer 1 GEMM: x (fp32) -> HW8A
  mfma_gemm<<<gGemm, blk, 0, stream>>>(x, WT, DINV, HW8A, n);
  // gather1 + GEMM2 fused: HW8A -> HW8B
  gather_fuse<<<gFuse, dim3(512), 0, stream>>>(ROWS, CNT, COL, HW8A, DINV, b1, WT + 128 * 128, HW8B, n);
  // gather2 + GEMM3 fused: HW8B -> HW8A
  gather_fuse<<<gFuse, dim3(512), 0, stream>>>(ROWS, CNT, COL, HW8B, DINV, b2, WT + 2 * 128 * 128, HW8A, n);
  // gather3 (no GEMM): 256-thread no-barrier version, HW8A -> GCN (bf16)
  gather_k<<<gGather, blk, 0, stream>>>(ROWS, CNT, COL, HW8A, DINV, b3, GCN, n);

  // pool partials
  pool_kernel<<<POOL_GRID, blk, 0, stream>>>(GCN, PS, PM, n);

  // head 1 (pool finalized inline; exp+sum+argmax fused; 2 cols/thread)
  head_fused<<<gHeadHalf, blk, 0, stream>>>(n1W, n1b, g1, PS, PM, invn, nullptr, 0, EB1, &CELLS[0], SUM1, maxn, n);

  // conn mask from i1
  conn_kernel<<<gE, blk, 0, stream>>>(ei, E, &CELLS[0], CONN);

  // head 2
  head_fused<<<gHeadHalf, blk, 0, stream>>>(n2W, n2b, g2, PS, PM, invn, CONN, 1, EB2, &CELLS[1], SUM2, maxn, n);

  // normalize both heads + edge/stop head
  finish<<<gNorm + 1, blk, 0, stream>>>(EB1, SUM1, EB2, SUM2, out, maxn, GCN, eW, eb, ge, &CELLS[0], &CELLS[1]);
}